// Round 1
// 1211.522 us; speedup vs baseline: 1.0945x; 1.0945x over previous
//
#include <hip/hip_runtime.h>
#include <math.h>

#define NRES 1024
#define HH 8
#define CC 48
#define CZF 128

// ---------------------------------------------------------------------------
// K1: raw projections  raw[n][1632] = s[n][:] @ [wq|wkv|wkvp] + bias
// grid 512 = 128 n-tiles(8 rows) x 4 col-chunks(408)  -> 2 blocks/CU
__global__ __launch_bounds__(256) void k_proj(
    const float* __restrict__ s,
    const float* __restrict__ wq, const float* __restrict__ bq,
    const float* __restrict__ wkv, const float* __restrict__ bkv,
    const float* __restrict__ wkvp, const float* __restrict__ bkvp,
    float* __restrict__ raw)
{
  int bb = blockIdx.x;
  int n0 = (bb >> 2) * 8;
  int ch = bb & 3;
  int t = threadIdx.x;
  const float* srow = s + (size_t)n0 * 384;   // uniform reads -> scalar loads
  for (int ci = 0; ci < 2; ci++) {
    int local = ci * 256 + t;
    if (local >= 408) break;
    int col = ch * 408 + local;
    const float* w; int ld; float bias;
    if (col < 384)       { w = wq  + col;          ld = 384; bias = bq[col]; }
    else if (col < 1152) { w = wkv + (col - 384);  ld = 768; bias = bkv[col - 384]; }
    else                 { w = wkvp + (col - 1152); ld = 480; bias = bkvp[col - 1152]; }
    float acc[8];
#pragma unroll
    for (int r = 0; r < 8; r++) acc[r] = bias;
    for (int k = 0; k < 384; k++) {
      float wv = w[(size_t)k * ld];
#pragma unroll
      for (int r = 0; r < 8; r++) acc[r] = fmaf(srow[r * 384 + k], wv, acc[r]);
    }
#pragma unroll
    for (int r = 0; r < 8; r++) raw[(size_t)(n0 + r) * 1632 + col] = acc[r];
  }
}

// ---------------------------------------------------------------------------
// K1b: rotation + scaling + layout scatter.  grid 1024 (one block per n)
__global__ __launch_bounds__(256) void k_scatter(
    const float* __restrict__ raw, const float* __restrict__ rot,
    const float* __restrict__ gw,
    float* __restrict__ qp, float* __restrict__ kp, float* __restrict__ V2)
{
  int n = blockIdx.x, t = threadIdx.x;
  __shared__ float rsh[1632];
  __shared__ float hwsh[16];
  for (int i = t; i < 1632; i += 256) rsh[i] = raw[(size_t)n * 1632 + i];
  if (t < 16) hwsh[t] = log1pf(expf(gw[t])) * 0.25f;
  __syncthreads();
  float r00 = rot[n*9+0], r01 = rot[n*9+1], r02 = rot[n*9+2];
  float r10 = rot[n*9+3], r11 = rot[n*9+4], r12 = rot[n*9+5];
  float r20 = rot[n*9+6], r21 = rot[n*9+7], r22 = rot[n*9+8];
  for (int idx = t; idx < 768; idx += 256) {
    int isK = idx >= 384;
    int rem = idx - (isK ? 384 : 0);
    int h = rem / 48, gi = rem % 48, g = gi / 3, ii = gi % 3;
    int cb = isK ? (384 + h * 96 + g * 3) : (h * 48 + g * 3);
    float x = rsh[cb], y = rsh[cb + 1], zz = rsh[cb + 2];
    float d0 = r00 * x + r01 * y + r02 * zz;
    float d1 = r10 * x + r11 * y + r12 * zz;
    float d2 = r20 * x + r21 * y + r22 * zz;
    float val = (ii == 0) ? d0 : (ii == 1 ? d1 : d2);
    if (!isK) {
      val *= hwsh[g] * 0.57735026919f;           // hw[g] / sqrt(3)
      qp[(size_t)((h << 10) + n) * 48 + gi] = val;
    } else {
      kp[(size_t)((h << 10) + n) * 48 + gi] = val;
    }
  }
  for (int idx = t; idx < 768; idx += 256) {
    int h = idx / 96, c = idx % 96;
    float val = 0.f;
    if (c < 48) val = rsh[384 + h * 96 + 48 + c];
    else if (c < 84) {
      int pc = c - 48, pp = pc / 3, j = pc % 3;
      val = rsh[1152 + j * 160 + h * 20 + 8 + pp];
    }
    V2[(size_t)((h << 10) + n) * 96 + c] = val;
  }
}

// ---------------------------------------------------------------------------
// K2: S[h][n][m] = sqrt(1/3)*(z[n][m][:]@wb[:,h] + bb[h]) + INF*(mask_n*mask_m-1)
// REWRITE: register-direct z (no zsh staging, no per-chunk sync),
// 4 pair-rows per thread, wb in 2 LDS replicas. grid 4096 x 256, 256 pairs/blk.
__global__ __launch_bounds__(256) void k_bias(
    const float* __restrict__ z, const float* __restrict__ wb,
    const float* __restrict__ bb, const float* __restrict__ mask,
    float* __restrict__ S)
{
  __shared__ float wbrep[2][1032];   // 2 replicas (q>>1), 2-way conflicts only
  __shared__ float bbsh[8];
  int t = threadIdx.x;
  size_t pair0 = (size_t)blockIdx.x * 256;
  for (int idx = t; idx < 1024; idx += 256) {
    float v = wb[idx];
    wbrep[0][idx] = v; wbrep[1][idx] = v;
  }
  if (t < 8) bbsh[t] = bb[t];
  __syncthreads();
  int q = t & 3, r = t >> 2;         // q: c-quarter, r: base row 0..63
  const float* wbq = wbrep[q >> 1];
  float acc[4][8];
#pragma unroll
  for (int g = 0; g < 4; g++)
#pragma unroll
    for (int hh = 0; hh < 8; hh++) acc[g][hh] = 0.f;
  const float* zb = z + (pair0 + r) * 128;
#pragma unroll
  for (int i = 0; i < 8; i++) {
    int c = q * 4 + i * 16;
    float4 zf0 = *(const float4*)(zb + (size_t)0 * 8192 + c);
    float4 zf1 = *(const float4*)(zb + (size_t)1 * 8192 + c);
    float4 zf2 = *(const float4*)(zb + (size_t)2 * 8192 + c);
    float4 zf3 = *(const float4*)(zb + (size_t)3 * 8192 + c);
#pragma unroll
    for (int j = 0; j < 4; j++) {
      float4 w0 = *(const float4*)&wbq[(c + j) * 8];
      float4 w1 = *(const float4*)&wbq[(c + j) * 8 + 4];
      float z0 = (j == 0) ? zf0.x : (j == 1) ? zf0.y : (j == 2) ? zf0.z : zf0.w;
      float z1 = (j == 0) ? zf1.x : (j == 1) ? zf1.y : (j == 2) ? zf1.z : zf1.w;
      float z2 = (j == 0) ? zf2.x : (j == 1) ? zf2.y : (j == 2) ? zf2.z : zf2.w;
      float z3 = (j == 0) ? zf3.x : (j == 1) ? zf3.y : (j == 2) ? zf3.z : zf3.w;
      acc[0][0] = fmaf(z0, w0.x, acc[0][0]); acc[0][1] = fmaf(z0, w0.y, acc[0][1]);
      acc[0][2] = fmaf(z0, w0.z, acc[0][2]); acc[0][3] = fmaf(z0, w0.w, acc[0][3]);
      acc[0][4] = fmaf(z0, w1.x, acc[0][4]); acc[0][5] = fmaf(z0, w1.y, acc[0][5]);
      acc[0][6] = fmaf(z0, w1.z, acc[0][6]); acc[0][7] = fmaf(z0, w1.w, acc[0][7]);
      acc[1][0] = fmaf(z1, w0.x, acc[1][0]); acc[1][1] = fmaf(z1, w0.y, acc[1][1]);
      acc[1][2] = fmaf(z1, w0.z, acc[1][2]); acc[1][3] = fmaf(z1, w0.w, acc[1][3]);
      acc[1][4] = fmaf(z1, w1.x, acc[1][4]); acc[1][5] = fmaf(z1, w1.y, acc[1][5]);
      acc[1][6] = fmaf(z1, w1.z, acc[1][6]); acc[1][7] = fmaf(z1, w1.w, acc[1][7]);
      acc[2][0] = fmaf(z2, w0.x, acc[2][0]); acc[2][1] = fmaf(z2, w0.y, acc[2][1]);
      acc[2][2] = fmaf(z2, w0.z, acc[2][2]); acc[2][3] = fmaf(z2, w0.w, acc[2][3]);
      acc[2][4] = fmaf(z2, w1.x, acc[2][4]); acc[2][5] = fmaf(z2, w1.y, acc[2][5]);
      acc[2][6] = fmaf(z2, w1.z, acc[2][6]); acc[2][7] = fmaf(z2, w1.w, acc[2][7]);
      acc[3][0] = fmaf(z3, w0.x, acc[3][0]); acc[3][1] = fmaf(z3, w0.y, acc[3][1]);
      acc[3][2] = fmaf(z3, w0.z, acc[3][2]); acc[3][3] = fmaf(z3, w0.w, acc[3][3]);
      acc[3][4] = fmaf(z3, w1.x, acc[3][4]); acc[3][5] = fmaf(z3, w1.y, acc[3][5]);
      acc[3][6] = fmaf(z3, w1.z, acc[3][6]); acc[3][7] = fmaf(z3, w1.w, acc[3][7]);
    }
  }
#pragma unroll
  for (int g = 0; g < 4; g++)
#pragma unroll
    for (int hh = 0; hh < 8; hh++) {
      acc[g][hh] += __shfl_xor(acc[g][hh], 1, 64);
      acc[g][hh] += __shfl_xor(acc[g][hh], 2, 64);
    }
  const float is3 = 0.57735026919f;
  int h0 = q * 2;
#pragma unroll
  for (int g = 0; g < 4; g++) {
    size_t pair = pair0 + r + (size_t)g * 64;
    int n = (int)(pair >> 10), m = (int)(pair & 1023);
    float mt = 100000.0f * (mask[n] * mask[m] - 1.0f);
    S[(size_t)h0 * 1048576 + pair]       = (acc[g][h0] + bbsh[h0]) * is3 + mt;
    S[(size_t)(h0 + 1) * 1048576 + pair] = (acc[g][h0 + 1] + bbsh[h0 + 1]) * is3 + mt;
  }
}

// ---------------------------------------------------------------------------
// K3: scores + bias + softmax (in-place into S). grid 1024 = 8h x 128 tiles(8 n)
__global__ __launch_bounds__(256) void k_attn(
    const float* __restrict__ qp, const float* __restrict__ kp,
    float* __restrict__ S)
{
  int b = blockIdx.x;
  int h = b >> 7, n0 = (b & 127) * 8;
  int t = threadIdx.x;
  __shared__ float ksh[128 * 52];   // 128 k-rows, stride 52 (pad for banks)
  __shared__ float ssh[8 * 1024];
  int ms = t & 127, nh = t >> 7;
  const float* qbase = qp + (size_t)((h << 10) + n0 + nh * 4) * 48;
  size_t Sbase = (size_t)h * 1048576 + (size_t)n0 * 1024;
  for (int cb = 0; cb < 1024; cb += 128) {
    __syncthreads();
    for (int idx = t; idx < 1536; idx += 256) {
      int r = idx / 12, p = idx % 12;
      float4 f = *(const float4*)(kp + (size_t)((h << 10) + cb + r) * 48 + p * 4);
      *(float4*)&ksh[r * 52 + p * 4] = f;
    }
    __syncthreads();
    int m = cb + ms;
    float a0 = 0.f, a1 = 0.f, a2 = 0.f, a3 = 0.f;
#pragma unroll
    for (int ic = 0; ic < 12; ic++) {
      float4 kf = *(const float4*)&ksh[ms * 52 + ic * 4];
      float4 q0 = *(const float4*)(qbase + 0 * 48 + ic * 4);
      float4 q1 = *(const float4*)(qbase + 1 * 48 + ic * 4);
      float4 q2 = *(const float4*)(qbase + 2 * 48 + ic * 4);
      float4 q3 = *(const float4*)(qbase + 3 * 48 + ic * 4);
      a0 += q0.x * kf.x + q0.y * kf.y + q0.z * kf.z + q0.w * kf.w;
      a1 += q1.x * kf.x + q1.y * kf.y + q1.z * kf.z + q1.w * kf.w;
      a2 += q2.x * kf.x + q2.y * kf.y + q2.z * kf.z + q2.w * kf.w;
      a3 += q3.x * kf.x + q3.y * kf.y + q3.z * kf.z + q3.w * kf.w;
    }
    int rb = nh * 4;
    ssh[(rb + 0) * 1024 + m] = a0 + S[Sbase + (size_t)(rb + 0) * 1024 + m];
    ssh[(rb + 1) * 1024 + m] = a1 + S[Sbase + (size_t)(rb + 1) * 1024 + m];
    ssh[(rb + 2) * 1024 + m] = a2 + S[Sbase + (size_t)(rb + 2) * 1024 + m];
    ssh[(rb + 3) * 1024 + m] = a3 + S[Sbase + (size_t)(rb + 3) * 1024 + m];
  }
  __syncthreads();
  int row = t >> 5, lane = t & 31;
  float* sr = ssh + row * 1024;
  float mx = -1e30f;
  for (int j = lane; j < 1024; j += 32) mx = fmaxf(mx, sr[j]);
#pragma unroll
  for (int o = 16; o >= 1; o >>= 1) mx = fmaxf(mx, __shfl_xor(mx, o, 32));
  float sum = 0.f;
  for (int j = lane; j < 1024; j += 32) {
    float e = __expf(sr[j] - mx);
    sr[j] = e; sum += e;
  }
#pragma unroll
  for (int o = 16; o >= 1; o >>= 1) sum += __shfl_xor(sum, o, 32);
  float inv = 1.0f / sum;
  float* Sout = S + Sbase + (size_t)row * 1024;
  for (int j = lane; j < 1024; j += 32) Sout[j] = sr[j] * inv;
}

// ---------------------------------------------------------------------------
// K4: o / o_pt / norms -> F cols [0..767]. grid 512 = 8h x 64 tiles(16 n)
// REWRITE: stage transposed a-tile ONCE (no per-chunk staging/sync),
// stream V2 direct from global. LDS 79.9 KB -> 2 blocks/CU.
__global__ __launch_bounds__(256) void k_av(
    const float* __restrict__ S, const float* __restrict__ V2,
    float* __restrict__ F)
{
  int b = blockIdx.x;
  int h = b >> 6, n0 = (b & 63) * 16;
  int t = threadIdx.x;
  __shared__ float asT[1024 * 18];  // [m][nn], stride 18 (pad: 4-way max)
  __shared__ float fsh[16 * 96];
  size_t Sbase = (size_t)h * 1048576 + (size_t)n0 * 1024;
  for (int idx = t; idx < 16384; idx += 256) {
    int nn = idx >> 10, m = idx & 1023;
    asT[m * 18 + nn] = S[Sbase + (size_t)nn * 1024 + m];
  }
  __syncthreads();
  int np = t >> 5, c4 = t & 31;
  float4 a0 = {0,0,0,0}, a1 = {0,0,0,0};
  if (c4 < 24) {
    const float* vbase = V2 + (size_t)(h << 10) * 96 + c4 * 4;
#pragma unroll 4
    for (int mm = 0; mm < 1024; mm++) {
      float4 vv = *(const float4*)(vbase + (size_t)mm * 96);
      float2 av = *(const float2*)&asT[mm * 18 + np * 2];
      a0.x += av.x * vv.x; a0.y += av.x * vv.y; a0.z += av.x * vv.z; a0.w += av.x * vv.w;
      a1.x += av.y * vv.x; a1.y += av.y * vv.y; a1.z += av.y * vv.z; a1.w += av.y * vv.w;
    }
    *(float4*)&fsh[(np * 2 + 0) * 96 + c4 * 4] = a0;
    *(float4*)&fsh[(np * 2 + 1) * 96 + c4 * 4] = a1;
  }
  __syncthreads();
  for (int idx = t; idx < 768; idx += 256) {
    int nn = idx / 48, c = idx % 48;
    F[(size_t)(n0 + nn) * 1024 + h * 48 + c] = fsh[nn * 96 + c];
  }
  for (int idx = t; idx < 192; idx += 256) {
    int nn = idx / 12, pp = idx % 12;
    float x = fsh[nn * 96 + 48 + pp * 3];
    float y = fsh[nn * 96 + 48 + pp * 3 + 1];
    float zz = fsh[nn * 96 + 48 + pp * 3 + 2];
    size_t base = (size_t)(n0 + nn) * 1024;
    F[base + 384 + h * 12 + pp] = x;
    F[base + 480 + h * 12 + pp] = y;
    F[base + 576 + h * 12 + pp] = zz;
    F[base + 672 + h * 12 + pp] = sqrtf(x * x + y * y + zz * zz + 1e-8f);
  }
}

// ---------------------------------------------------------------------------
// K5: tmp[n][h*128+c] = sum_m a[h][n][m] * z[n][m][c].  grid 1024 (block per n)
// REWRITE: stage a-rows (8h x 1024m, 32 KB) ONCE; stream z direct from global
// (each element consumed by exactly one thread; 2x512B/wave coalesced).
__global__ __launch_bounds__(256) void k_az(
    const float* __restrict__ S, const float* __restrict__ z,
    float* __restrict__ tmp)
{
  int n = blockIdx.x, t = threadIdx.x;
  __shared__ float ash[8192];      // [m][h] stride 8; reused for reduction
  int mg = t >> 5, c4 = t & 31;
  for (int idx = t; idx < 8192; idx += 256) {
    int hh = idx >> 10, m = idx & 1023;
    ash[m * 8 + hh] = S[(size_t)hh * 1048576 + (size_t)n * 1024 + m];
  }
  __syncthreads();
  float4 acc[8];
#pragma unroll
  for (int hh = 0; hh < 8; hh++) acc[hh] = {0.f, 0.f, 0.f, 0.f};
  const float4* zn = (const float4*)(z + (size_t)n * 131072);
#pragma unroll 4
  for (int k2 = 0; k2 < 128; k2++) {
    int mm = k2 * 8 + mg;
    float4 zf = zn[mm * 32 + c4];
    float4 av0 = *(const float4*)&ash[mm * 8];
    float4 av1 = *(const float4*)&ash[mm * 8 + 4];
    acc[0].x += av0.x*zf.x; acc[0].y += av0.x*zf.y; acc[0].z += av0.x*zf.z; acc[0].w += av0.x*zf.w;
    acc[1].x += av0.y*zf.x; acc[1].y += av0.y*zf.y; acc[1].z += av0.y*zf.z; acc[1].w += av0.y*zf.w;
    acc[2].x += av0.z*zf.x; acc[2].y += av0.z*zf.y; acc[2].z += av0.z*zf.z; acc[2].w += av0.z*zf.w;
    acc[3].x += av0.w*zf.x; acc[3].y += av0.w*zf.y; acc[3].z += av0.w*zf.z; acc[3].w += av0.w*zf.w;
    acc[4].x += av1.x*zf.x; acc[4].y += av1.x*zf.y; acc[4].z += av1.x*zf.z; acc[4].w += av1.x*zf.w;
    acc[5].x += av1.y*zf.x; acc[5].y += av1.y*zf.y; acc[5].z += av1.y*zf.z; acc[5].w += av1.y*zf.w;
    acc[6].x += av1.z*zf.x; acc[6].y += av1.z*zf.y; acc[6].z += av1.z*zf.z; acc[6].w += av1.z*zf.w;
    acc[7].x += av1.w*zf.x; acc[7].y += av1.w*zf.y; acc[7].z += av1.w*zf.z; acc[7].w += av1.w*zf.w;
  }
  __syncthreads();
#pragma unroll
  for (int hh = 0; hh < 8; hh++)
    *(float4*)&ash[mg * 1024 + hh * 128 + c4 * 4] = acc[hh];
  __syncthreads();
  for (int idx = t; idx < 1024; idx += 256) {
    float sv = 0.f;
#pragma unroll
    for (int g2 = 0; g2 < 8; g2++) sv += ash[g2 * 1024 + idx];
    tmp[(size_t)n * 1024 + idx] = sv;
  }
}

// ---------------------------------------------------------------------------
// K6: o_pair = tmp@wdz+bdz ; feats assembly ; out = feats@wout + bout
// grid 512 (2 n per block) -> 2 blocks/CU for latency hiding
__global__ __launch_bounds__(256) void k_out(
    const float* __restrict__ F, const float* __restrict__ tmp,
    const float* __restrict__ wdz, const float* __restrict__ bdz,
    const float* __restrict__ wout, const float* __restrict__ bout,
    float* __restrict__ out)
{
  int n0 = blockIdx.x * 2, t = threadIdx.x;
  __shared__ float fsh[2 * 1024];
  for (int idx = t; idx < 1536; idx += 256) {
    int nn = idx / 768, c = idx % 768;
    fsh[nn * 1024 + c] = F[(size_t)(n0 + nn) * 1024 + c];
  }
  {
    int h = t >> 5, d = t & 31;
#pragma unroll
    for (int nn = 0; nn < 2; nn++) {
      float acc = bdz[d];
      const float* tr = tmp + (size_t)(n0 + nn) * 1024 + h * 128;
      for (int c = 0; c < 128; c++) acc = fmaf(tr[c], wdz[c * 32 + d], acc);
      fsh[nn * 1024 + 768 + h * 32 + d] = acc;
    }
  }
  __syncthreads();
  int j = t & 127, kh = t >> 7;
  float a[3][2];
#pragma unroll
  for (int jj = 0; jj < 3; jj++)
#pragma unroll
    for (int r = 0; r < 2; r++) a[jj][r] = 0.f;
  const float4* f4p = (const float4*)fsh;
  for (int k4 = kh * 128; k4 < kh * 128 + 128; k4++) {
    float4 f0 = f4p[k4];
    float4 f1 = f4p[256 + k4];
    int k = k4 * 4;
#pragma unroll
    for (int u = 0; u < 4; u++) {
      float w0 = wout[(size_t)(k + u) * 384 + j];
      float w1 = wout[(size_t)(k + u) * 384 + j + 128];
      float w2 = wout[(size_t)(k + u) * 384 + j + 256];
      float e0 = (u == 0) ? f0.x : (u == 1) ? f0.y : (u == 2) ? f0.z : f0.w;
      float e1 = (u == 0) ? f1.x : (u == 1) ? f1.y : (u == 2) ? f1.z : f1.w;
      a[0][0] = fmaf(e0, w0, a[0][0]); a[0][1] = fmaf(e1, w0, a[0][1]);
      a[1][0] = fmaf(e0, w1, a[1][0]); a[1][1] = fmaf(e1, w1, a[1][1]);
      a[2][0] = fmaf(e0, w2, a[2][0]); a[2][1] = fmaf(e1, w2, a[2][1]);
    }
  }
  __syncthreads();   // done reading fsh; reuse as reduction scratch
  if (kh == 1) {
#pragma unroll
    for (int jj = 0; jj < 3; jj++)
#pragma unroll
      for (int r = 0; r < 2; r++)
        fsh[(jj * 2 + r) * 128 + j] = a[jj][r];
  }
  __syncthreads();
  if (kh == 0) {
#pragma unroll
    for (int jj = 0; jj < 3; jj++)
#pragma unroll
      for (int r = 0; r < 2; r++) {
        float v = a[jj][r] + fsh[(jj * 2 + r) * 128 + j] + bout[jj * 128 + j];
        out[(size_t)(n0 + r) * 384 + jj * 128 + j] = v;
      }
  }
}

// ---------------------------------------------------------------------------
extern "C" void kernel_launch(void* const* d_in, const int* in_sizes, int n_in,
                              void* d_out, int out_size, void* d_ws, size_t ws_size,
                              hipStream_t stream) {
  const float* s    = (const float*)d_in[0];
  const float* z    = (const float*)d_in[1];
  const float* rot  = (const float*)d_in[2];
  const float* mask = (const float*)d_in[3];
  const float* wq   = (const float*)d_in[4];
  const float* bq   = (const float*)d_in[5];
  const float* wkv  = (const float*)d_in[6];
  const float* bkv  = (const float*)d_in[7];
  const float* wkvp = (const float*)d_in[8];
  const float* bkvp = (const float*)d_in[9];
  const float* wb   = (const float*)d_in[10];
  const float* bb   = (const float*)d_in[11];
  const float* wdz  = (const float*)d_in[12];
  const float* bdz  = (const float*)d_in[13];
  const float* wout = (const float*)d_in[14];
  const float* bout = (const float*)d_in[15];
  const float* gw   = (const float*)d_in[16];
  float* out = (float*)d_out;

  float* ws  = (float*)d_ws;
  float* raw = ws;                       // 1024*1632
  float* qp  = raw + 1024 * 1632;        // 8*1024*48
  float* kp  = qp + 393216;              // 8*1024*48
  float* V2  = kp + 393216;              // 8*1024*96
  float* S   = V2 + 786432;              // 8*1024*1024
  float* tmp = S + 8388608;              // 1024*1024
  float* F   = tmp + 1048576;            // 1024*1024

  k_proj<<<512, 256, 0, stream>>>(s, wq, bq, wkv, bkv, wkvp, bkvp, raw);
  k_scatter<<<1024, 256, 0, stream>>>(raw, rot, gw, qp, kp, V2);
  k_bias<<<4096, 256, 0, stream>>>(z, wb, bb, mask, S);
  k_attn<<<1024, 256, 0, stream>>>(qp, kp, S);
  k_av<<<512, 256, 0, stream>>>(S, V2, F);
  k_az<<<1024, 256, 0, stream>>>(S, z, tmp);
  k_out<<<512, 256, 0, stream>>>(F, tmp, wdz, bdz, wout, bout, out);
}